// Round 7
// baseline (642.470 us; speedup 1.0000x reference)
//
#include <hip/hip_runtime.h>
#include <math.h>

#define Nn 50000
#define Ee 800000
#define Bb 8
#define ROUNDS 4
#define KWVB 512            // kwv partial blocks (2/CU)
#define SCB 196             // scan blocks (196*256 = 50176 >= Nn)
#define HP 132              // kwv fp32 h_s row stride (128 + 4 pad)
#define KS 40               // kwv bf16 transposed row stride in shorts
#define HTT 136             // A/hnT bf16 full-row stride in shorts (128 + 8 pad, 16B-aligned)
#define NBK 196             // dst buckets (dst >> 8)
#define P1B 391             // partition blocks
#define CHUNK 2047          // edges per partition block (391*2047 >= Ee)

typedef __attribute__((ext_vector_type(8))) short bf16x8;
typedef __attribute__((ext_vector_type(4))) float f32x4;

__device__ inline short f2bf(float f) {
  union { float f; unsigned u; } v; v.f = f;
  unsigned r = v.u + 0x7fff + ((v.u >> 16) & 1);  // RNE
  return (short)(r >> 16);
}
__device__ inline float bf2f(short s) {
  union { float f; unsigned u; } v; v.u = ((unsigned)(unsigned short)s) << 16;
  return v.f;
}

// ---------------------------------------------------------------- encode + fused segmean
__global__ __launch_bounds__(256) void encode_seg(
    const float* __restrict__ x, const float* __restrict__ xm,
    const int* __restrict__ batch, const float* __restrict__ W,
    const float* __restrict__ b, float* __restrict__ h,
    float* __restrict__ gsum, float* __restrict__ gcnt,
    float* __restrict__ bcsum, float* __restrict__ bccnt) {
  __shared__ float xs5[128 * 5];
  __shared__ float xm3[128 * 3];
  __shared__ float ls[Bb * 128];
  __shared__ float lb[Bb * 128];
  __shared__ float lc[Bb], lbc[Bb];
  const int t = threadIdx.x;
  const int nBase = blockIdx.x * 128;
  const int j = t & 127, half = t >> 7;
  const int base5 = nBase * 5, base3 = nBase * 3;
  for (int q = t; q < 640; q += 256) xs5[q] = (base5 + q < Nn * 5) ? x[base5 + q] : 0.f;
  for (int q = t; q < 384; q += 256) xm3[q] = (base3 + q < Nn * 3) ? xm[base3 + q] : 0.f;
  for (int q = t; q < Bb * 128; q += 256) { ls[q] = 0.f; lb[q] = 0.f; }
  if (t < Bb) { lc[t] = 0.f; lbc[t] = 0.f; }
  float Wcol[8];
#pragma unroll
  for (int k = 0; k < 8; k++) Wcol[k] = W[k * 128 + j];
  const float bj = b[j];
  __syncthreads();
  int curb = -1;
  float runh = 0.f, runb = 0.f, runc = 0.f, runbc = 0.f;
  for (int kk = 0; kk < 64; kk++) {
    int i = nBase + kk * 2 + half;
    if (i >= Nn) break;
    int li = i - nBase;
    float acc = bj;
#pragma unroll
    for (int k = 0; k < 5; k++) acc = fmaf(xs5[li * 5 + k], Wcol[k], acc);
#pragma unroll
    for (int k = 0; k < 3; k++) acc = fmaf(xm3[li * 3 + k], Wcol[5 + k], acc);
    float v = fmaxf(acc, 0.f);
    h[(size_t)i * 128 + j] = v;
    float bc = xm3[li * 3 + 2];
    int g = batch[i];
    if (g != curb) {
      if (curb >= 0) {
        atomicAdd(&ls[curb * 128 + j], runh);
        atomicAdd(&lb[curb * 128 + j], runb);
        if (j == 0) { atomicAdd(&lc[curb], runc); atomicAdd(&lbc[curb], runbc); }
      }
      curb = g; runh = runb = runc = runbc = 0.f;
    }
    runh += v; runb += v * bc;
    if (j == 0) { runc += 1.f; runbc += bc; }
  }
  if (curb >= 0) {
    atomicAdd(&ls[curb * 128 + j], runh);
    atomicAdd(&lb[curb * 128 + j], runb);
    if (j == 0) { atomicAdd(&lc[curb], runc); atomicAdd(&lbc[curb], runbc); }
  }
  __syncthreads();
  for (int q = t; q < Bb * 128; q += 256) {
    float a = ls[q], c = lb[q];
    if (a != 0.f) atomicAdd(&gsum[q], a);
    if (c != 0.f) atomicAdd(&bcsum[q], c);
  }
  if (t < Bb) { atomicAdd(&gcnt[t], lc[t]); atomicAdd(&bccnt[t], lbc[t]); }
}

// ---------------------------------------------------------------- CSR build (radix partition)
// bkt_cnt also absorbs the one-shot weight split (blocks 0..255, one elem/thread)
__global__ __launch_bounds__(256) void bkt_cnt(
    const int* __restrict__ ei, int* __restrict__ bktcnt,
    const float* __restrict__ Wm, const float* __restrict__ Wu,
    short* __restrict__ Wmt_h, short* __restrict__ Wmt_l,
    short* __restrict__ Wut_h, short* __restrict__ Wut_l) {
  __shared__ int hist[NBK];
  int t = threadIdx.x;
  // fused split_w
  int idx = blockIdx.x * 256 + t;
  if (idx < 32768) {
    int k = idx & 127, n = (idx >> 7) & 127, y = idx >> 14;
    float w = Wm[(size_t)(y * 128 + k) * 128 + n];
    short hi = f2bf(w);
    Wmt_h[idx] = hi;
    Wmt_l[idx] = f2bf(w - bf2f(hi));
  } else if (idx < 65536) {
    int j = idx - 32768;
    int k = j & 255, n = j >> 8;
    float w = Wu[(size_t)k * 128 + n];
    short hi = f2bf(w);
    Wut_h[j] = hi;
    Wut_l[j] = f2bf(w - bf2f(hi));
  }
  for (int q = t; q < NBK; q += 256) hist[q] = 0;
  __syncthreads();
  int base = blockIdx.x * CHUNK;
  int end = base + CHUNK < Ee ? base + CHUNK : Ee;
  for (int e = base + t; e < end; e += 256) atomicAdd(&hist[ei[Ee + e] >> 8], 1);
  __syncthreads();
  for (int q = t; q < NBK; q += 256)
    if (hist[q]) atomicAdd(&bktcnt[q], hist[q]);
}
__global__ __launch_bounds__(256) void bkt_scan(const int* __restrict__ bktcnt,
                                                int* __restrict__ bktbase,
                                                int* __restrict__ bktcur) {
  __shared__ int s[256];
  int t = threadIdx.x;
  int v = (t < NBK) ? bktcnt[t] : 0;
  s[t] = v;
  __syncthreads();
  for (int off = 1; off < 256; off <<= 1) {
    int x = (t >= off) ? s[t - off] : 0;
    __syncthreads();
    s[t] += x;
    __syncthreads();
  }
  int ex = s[t] - v;
  if (t < NBK) { bktbase[t] = ex; bktcur[t] = ex; }
  if (t == NBK - 1) bktbase[NBK] = ex + v;
}
__global__ __launch_bounds__(256) void bkt_part(
    const int* __restrict__ ei, const float* __restrict__ ea,
    int* __restrict__ bktcur, int2* __restrict__ recA,
    unsigned char* __restrict__ dlo) {
  __shared__ int hist[NBK], lbase[NBK], lcur[NBK];
  int t = threadIdx.x;
  for (int q = t; q < NBK; q += 256) hist[q] = 0;
  __syncthreads();
  int base = blockIdx.x * CHUNK;
  int end = base + CHUNK < Ee ? base + CHUNK : Ee;
  for (int e = base + t; e < end; e += 256) atomicAdd(&hist[ei[Ee + e] >> 8], 1);
  __syncthreads();
  for (int q = t; q < NBK; q += 256) {
    int c = hist[q];
    lbase[q] = c ? atomicAdd(&bktcur[q], c) : 0;
    lcur[q] = 0;
  }
  __syncthreads();
  for (int e = base + t; e < end; e += 256) {
    int d = ei[Ee + e];
    int bk = d >> 8;
    int p = lbase[bk] + atomicAdd(&lcur[bk], 1);
    unsigned r0 = (unsigned)ei[e] |
                  ((unsigned)(unsigned short)f2bf(ea[3 * (size_t)e + 0]) << 16);
    unsigned r1 = (unsigned)(unsigned short)f2bf(ea[3 * (size_t)e + 1]) |
                  ((unsigned)(unsigned short)f2bf(ea[3 * (size_t)e + 2]) << 16);
    recA[p] = make_int2((int)r0, (int)r1);
    dlo[p] = (unsigned char)(d & 255);
  }
}
// dst_cnt + per-block sum fused (bucket b == scan block b: 256-dst range)
__global__ __launch_bounds__(256) void dst_cnt_bsum(
    const int* __restrict__ bktbase, const unsigned char* __restrict__ dlo,
    int* __restrict__ cnt, int* __restrict__ bsum) {
  __shared__ int hh[256];
  __shared__ int wsum[4];
  int t = threadIdx.x;
  hh[t] = 0;
  __syncthreads();
  int b = blockIdx.x;
  int lo = bktbase[b], hi = bktbase[b + 1];
  for (int i = lo + t; i < hi; i += 256) atomicAdd(&hh[dlo[i]], 1);
  __syncthreads();
  int d = b * 256 + t;
  int v = hh[t];
  if (d < Nn) cnt[d] = v;
#pragma unroll
  for (int off = 32; off > 0; off >>= 1) v += __shfl_down(v, off);
  if ((t & 63) == 0) wsum[t >> 6] = v;
  __syncthreads();
  if (t == 0) bsum[b] = wsum[0] + wsum[1] + wsum[2] + wsum[3];
}
__global__ __launch_bounds__(256) void scan_top_kernel(const int* __restrict__ bsum,
                                                       int* __restrict__ boff) {
  __shared__ int s[256];
  int t = threadIdx.x;
  int v = (t < SCB) ? bsum[t] : 0;
  s[t] = v;
  __syncthreads();
  for (int off = 1; off < 256; off <<= 1) {
    int x = (t >= off) ? s[t - off] : 0;
    __syncthreads();
    s[t] += x;
    __syncthreads();
  }
  boff[t] = s[t] - v;  // exclusive
}
// apply (local scan -> rowptr/invdeg) + bkt_fin (scatter) fused
__global__ __launch_bounds__(256) void apply_fin(
    const int* __restrict__ cnt, const int* __restrict__ boff,
    const int* __restrict__ bktbase, const int2* __restrict__ recA,
    const unsigned char* __restrict__ dlo,
    int* __restrict__ rowptr, float* __restrict__ invdeg,
    int2* __restrict__ rec) {
  __shared__ int s[256];
  __shared__ int cur[256];
  int t = threadIdx.x, b = blockIdx.x;
  int i = b * 256 + t;
  int v = (i < Nn) ? cnt[i] : 0;
  s[t] = v;
  __syncthreads();
  for (int off = 1; off < 256; off <<= 1) {
    int x = (t >= off) ? s[t - off] : 0;
    __syncthreads();
    s[t] += x;
    __syncthreads();
  }
  int ex = boff[b] + s[t] - v;
  if (i < Nn) {
    rowptr[i] = ex;
    invdeg[i] = 1.0f / fmaxf((float)v, 1.0f);
    if (i == Nn - 1) rowptr[Nn] = ex + v;
  }
  cur[t] = ex;
  __syncthreads();
  int lo = bktbase[b], hi = bktbase[b + 1];
  for (int ii = lo + t; ii < hi; ii += 256) {
    int dl = dlo[ii];
    int p = atomicAdd(&cur[dl], 1);
    rec[p] = recA[ii];
  }
}

// ---------------------------------------------------------------- round-0 proj (standalone, 32-row tiles)
// hs8 (fp8 e4m3) = h @ Wm[0:128] ; hdbf (bf16) = h @ Wm[128:256]
// A staged in LDS (8.7 KB); B direct from L2-hot Wth. Grid 1563 -> 6 blocks/CU.
// Blocks 0..7 also compute gbst (once) and gb_0.
__global__ __launch_bounds__(256) void proj_mfma(
    const float* __restrict__ h, const short* __restrict__ Wth,
    unsigned char* __restrict__ hs8, unsigned short* __restrict__ hdbf,
    const float* __restrict__ bcsum, const float* __restrict__ bccnt,
    const float* __restrict__ bu, const float* __restrict__ Wu,
    float* __restrict__ gbst, const float* __restrict__ gsum_in,
    const float* __restrict__ gcnt, float* __restrict__ gb_out) {
  __shared__ short Ah[32 * HTT];
  const int t = threadIdx.x;
  const int nBase = blockIdx.x * 32;
  const int wave = t >> 6, lane = t & 63;
  const int ml = lane & 15, quad = lane >> 4;
  const int ko = quad * 8;

  // ---- gb prologue (blocks 0..7; Ah reused as float scratch, barrier-fenced)
  if (blockIdx.x < Bb) {
    float* xgs = (float*)Ah;
    const int g = blockIdx.x;
    if (t < 128) xgs[t] = bcsum[g * 128 + t] / fmaxf(bccnt[g], 1.f);
    __syncthreads();
    if (t < 128) {
      float a = bu[t];
#pragma unroll 4
      for (int k = 0; k < 128; k++) a = fmaf(xgs[k], Wu[(size_t)(384 + k) * 128 + t], a);
      gbst[g * 128 + t] = a;
    }
    __syncthreads();
    if (t < 128) xgs[t] = gsum_in[g * 128 + t] / fmaxf(gcnt[g], 1.f);
    __syncthreads();
    if (t < 128) {
      float a = gbst[g * 128 + t];
#pragma unroll 4
      for (int k = 0; k < 128; k++) a = fmaf(xgs[k], Wu[(size_t)(256 + k) * 128 + t], a);
      gb_out[g * 128 + t] = a;
    }
    __syncthreads();   // xgs dead before Ah staging writes
  }

  const int ar = t >> 3;                // 32 A-rows, 8 threads/row
  const int cb = (t & 7) * 16;          // 16 contiguous cols/thread
  const int nd0 = nBase + ar;
  const int nn = nd0 < Nn ? nd0 : Nn - 1;

  {
    const float* p = &h[(size_t)nn * 128 + cb];
#pragma unroll
    for (int jj = 0; jj < 2; jj++) {
      float4 u0 = *(const float4*)(p + jj * 8);
      float4 u1 = *(const float4*)(p + jj * 8 + 4);
      float xs[8] = {u0.x, u0.y, u0.z, u0.w, u1.x, u1.y, u1.z, u1.w};
      bf16x8 vh;
#pragma unroll
      for (int j = 0; j < 8; j++) vh[j] = f2bf(xs[j]);
      *(bf16x8*)&Ah[ar * HTT + cb + jj * 8] = vh;
    }
  }
  __syncthreads();

#pragma unroll 1
  for (int y = 0; y < 2; y++) {
    f32x4 pacc[2][2];
#pragma unroll
    for (int nt = 0; nt < 2; nt++)
#pragma unroll
      for (int mt = 0; mt < 2; mt++)
#pragma unroll
        for (int q = 0; q < 4; q++) pacc[nt][mt][q] = 0.f;
#pragma unroll
    for (int c = 0; c < 4; c++) {
      const bf16x8 b0 = *(const bf16x8*)&Wth[(size_t)(y * 128 + wave * 32 + ml) * 128 + c * 32 + ko];
      const bf16x8 b1 = *(const bf16x8*)&Wth[(size_t)(y * 128 + wave * 32 + 16 + ml) * 128 + c * 32 + ko];
#pragma unroll
      for (int mt = 0; mt < 2; mt++) {
        bf16x8 ah = *(const bf16x8*)&Ah[(mt * 16 + ml) * HTT + c * 32 + ko];
        pacc[0][mt] = __builtin_amdgcn_mfma_f32_16x16x32_bf16(ah, b0, pacc[0][mt], 0, 0, 0);
        pacc[1][mt] = __builtin_amdgcn_mfma_f32_16x16x32_bf16(ah, b1, pacc[1][mt], 0, 0, 0);
      }
    }
    if (y == 0) {
#pragma unroll
      for (int nt = 0; nt < 2; nt++) {
        const int ch = wave * 32 + nt * 16 + ml;
#pragma unroll
        for (int mt = 0; mt < 2; mt++) {
#pragma unroll
          for (int q = 0; q < 4; q++) {
            int nd = nBase + mt * 16 + quad * 4 + q;
            if (nd < Nn) {
              int pk = __builtin_amdgcn_cvt_pk_fp8_f32(pacc[nt][mt][q], pacc[nt][mt][q], 0, false);
              hs8[(size_t)nd * 128 + ch] = (unsigned char)(pk & 0xff);
            }
          }
        }
      }
    } else {
#pragma unroll
      for (int nt = 0; nt < 2; nt++) {
        const int ch = wave * 32 + nt * 16 + ml;
#pragma unroll
        for (int mt = 0; mt < 2; mt++) {
#pragma unroll
          for (int q = 0; q < 4; q++) {
            int nd = nBase + mt * 16 + quad * 4 + q;
            if (nd < Nn) hdbf[(size_t)nd * 128 + ch] = (unsigned short)f2bf(pacc[nt][mt][q]);
          }
        }
      }
    }
  }
}

// ---------------------------------------------------------------- edge pass / aggregation
// Blocks 0..7 (when dogb) also compute this round's gb from the previous
// round's gsum (kernel boundary: updg_{r-1} completed before agg_r starts).
__global__ __launch_bounds__(256) void agg_kernel(
    const unsigned char* __restrict__ hs8, const unsigned short* __restrict__ hdbf,
    unsigned short* __restrict__ aggbf, const int2* __restrict__ rec,
    const int* __restrict__ rowptr, const float* __restrict__ invdeg,
    const float* __restrict__ Wm, const float* __restrict__ bm,
    const float* __restrict__ Wu, const float* __restrict__ gbst,
    const float* __restrict__ gsum_in, const float* __restrict__ gcnt,
    float* __restrict__ gb_out, int dogb) {
  __shared__ float xgs[128];
  int t = threadIdx.x;
  if (dogb && blockIdx.x < Bb) {
    const int g = blockIdx.x;
    if (t < 128) xgs[t] = gsum_in[g * 128 + t] / fmaxf(gcnt[g], 1.f);
    __syncthreads();
    if (t < 128) {
      float a = gbst[g * 128 + t];
#pragma unroll 4
      for (int k = 0; k < 128; k++) a = fmaf(xgs[k], Wu[(size_t)(256 + k) * 128 + t], a);
      gb_out[g * 128 + t] = a;
    }
  }
  int hw = t >> 5, lane = t & 31;
  int v = blockIdx.x * 8 + hw;
  if (v >= Nn) return;
  int c0 = lane * 4;
  const float4 We0 = *(const float4*)&Wm[(size_t)256 * 128 + c0];
  const float4 We1 = *(const float4*)&Wm[(size_t)257 * 128 + c0];
  const float4 We2 = *(const float4*)&Wm[(size_t)258 * 128 + c0];
  const float4 b4  = *(const float4*)&bm[c0];
  const ushort4 hd4 = *(const ushort4*)&hdbf[(size_t)v * 128 + c0];
  const float bx = b4.x + bf2f((short)hd4.x), by = b4.y + bf2f((short)hd4.y),
              bz = b4.z + bf2f((short)hd4.z), bw = b4.w + bf2f((short)hd4.w);
  float ax = 0.f, ay = 0.f, az = 0.f, aw = 0.f;
  float ax2 = 0.f, ay2 = 0.f, az2 = 0.f, aw2 = 0.f;
  const int r0 = rowptr[v], r1 = rowptr[v + 1];
  int e = r0;
  for (; e + 2 <= r1; e += 2) {
    int2 q0 = rec[e], q1 = rec[e + 1];
    int s0 = q0.x & 0xffff, s1 = q1.x & 0xffff;
    unsigned hr0 = *(const unsigned*)&hs8[(size_t)s0 * 128 + c0];
    unsigned hr1 = *(const unsigned*)&hs8[(size_t)s1 * 128 + c0];
    float e00 = bf2f((short)(q0.x >> 16));
    float e01 = bf2f((short)(q0.y & 0xffff));
    float e02 = bf2f((short)(q0.y >> 16));
    float e10 = bf2f((short)(q1.x >> 16));
    float e11 = bf2f((short)(q1.y & 0xffff));
    float e12 = bf2f((short)(q1.y >> 16));
    float h0x = __builtin_amdgcn_cvt_f32_fp8(hr0, 0);
    float h0y = __builtin_amdgcn_cvt_f32_fp8(hr0, 1);
    float h0z = __builtin_amdgcn_cvt_f32_fp8(hr0, 2);
    float h0w = __builtin_amdgcn_cvt_f32_fp8(hr0, 3);
    float h1x = __builtin_amdgcn_cvt_f32_fp8(hr1, 0);
    float h1y = __builtin_amdgcn_cvt_f32_fp8(hr1, 1);
    float h1z = __builtin_amdgcn_cvt_f32_fp8(hr1, 2);
    float h1w = __builtin_amdgcn_cvt_f32_fp8(hr1, 3);
    ax += fmaxf(fmaf(e00, We0.x, fmaf(e01, We1.x, fmaf(e02, We2.x, h0x + bx))), 0.f);
    ay += fmaxf(fmaf(e00, We0.y, fmaf(e01, We1.y, fmaf(e02, We2.y, h0y + by))), 0.f);
    az += fmaxf(fmaf(e00, We0.z, fmaf(e01, We1.z, fmaf(e02, We2.z, h0z + bz))), 0.f);
    aw += fmaxf(fmaf(e00, We0.w, fmaf(e01, We1.w, fmaf(e02, We2.w, h0w + bw))), 0.f);
    ax2 += fmaxf(fmaf(e10, We0.x, fmaf(e11, We1.x, fmaf(e12, We2.x, h1x + bx))), 0.f);
    ay2 += fmaxf(fmaf(e10, We0.y, fmaf(e11, We1.y, fmaf(e12, We2.y, h1y + by))), 0.f);
    az2 += fmaxf(fmaf(e10, We0.z, fmaf(e11, We1.z, fmaf(e12, We2.z, h1z + bz))), 0.f);
    aw2 += fmaxf(fmaf(e10, We0.w, fmaf(e11, We1.w, fmaf(e12, We2.w, h1w + bw))), 0.f);
  }
  if (e < r1) {
    int2 q0 = rec[e];
    int s0 = q0.x & 0xffff;
    unsigned hr0 = *(const unsigned*)&hs8[(size_t)s0 * 128 + c0];
    float e00 = bf2f((short)(q0.x >> 16));
    float e01 = bf2f((short)(q0.y & 0xffff));
    float e02 = bf2f((short)(q0.y >> 16));
    float h0x = __builtin_amdgcn_cvt_f32_fp8(hr0, 0);
    float h0y = __builtin_amdgcn_cvt_f32_fp8(hr0, 1);
    float h0z = __builtin_amdgcn_cvt_f32_fp8(hr0, 2);
    float h0w = __builtin_amdgcn_cvt_f32_fp8(hr0, 3);
    ax += fmaxf(fmaf(e00, We0.x, fmaf(e01, We1.x, fmaf(e02, We2.x, h0x + bx))), 0.f);
    ay += fmaxf(fmaf(e00, We0.y, fmaf(e01, We1.y, fmaf(e02, We2.y, h0y + by))), 0.f);
    az += fmaxf(fmaf(e00, We0.z, fmaf(e01, We1.z, fmaf(e02, We2.z, h0z + bz))), 0.f);
    aw += fmaxf(fmaf(e00, We0.w, fmaf(e01, We1.w, fmaf(e02, We2.w, h0w + bw))), 0.f);
  }
  const float idg = invdeg[v];
  ushort4 o;
  o.x = (unsigned short)f2bf((ax + ax2) * idg);
  o.y = (unsigned short)f2bf((ay + ay2) * idg);
  o.z = (unsigned short)f2bf((az + az2) * idg);
  o.w = (unsigned short)f2bf((aw + aw2) * idg);
  *(ushort4*)&aggbf[(size_t)v * 128 + c0] = o;
}

// ---------------------------------------------------------------- fused update + proj (32-row tiles):
// phase B: h += relu(h@Wu[0:128] + agg@Wu[128:256] + gb)  (split-bf16 MFMA)
//   A staged in LDS (h half then agg half); B direct from L2-hot Wth/Wtl.
// epilogue: h write + group-sum + hnT (bf16) into LDS (aliases A buffer)
// phase C (doproj): hs8/hdbf of NEW h — A from hnT, B direct from global.
// LDS 25.6 KB + grid 1563 -> ~6 blocks/CU (was 3): latency-hiding via occupancy.
__global__ __launch_bounds__(256) void updg_proj(
    float* __restrict__ h, const unsigned short* __restrict__ aggbf,
    const int* __restrict__ batch,
    const short* __restrict__ Wth, const short* __restrict__ Wtl,
    const float* __restrict__ gb, float* __restrict__ gsum_out,
    const short* __restrict__ Wmth, unsigned char* __restrict__ hs8,
    unsigned short* __restrict__ hdbf, int doproj) {
  __shared__ short ms[2 * 32 * HTT];   // Ah | Al (17.4 KB); hnT aliases Ah
  __shared__ float gbs[Bb * 128];
  __shared__ float ls[Bb * 128];
  short* Ah = ms;                      // 32*HTT shorts
  short* Al = ms + 32 * HTT;
  short* hnT = ms;

  const int t = threadIdx.x;
  const int nBase = blockIdx.x * 32;
  *(float4*)&gbs[t * 4] = *(const float4*)&gb[t * 4];
#pragma unroll
  for (int q = 0; q < 4; q++) ls[t + q * 256] = 0.f;

  const int wave = t >> 6, lane = t & 63;
  const int ml = lane & 15, quad = lane >> 4;
  const int ko = quad * 8;

  f32x4 acc[2][2];
#pragma unroll
  for (int nt = 0; nt < 2; nt++)
#pragma unroll
    for (int mt = 0; mt < 2; mt++)
#pragma unroll
      for (int q = 0; q < 4; q++) acc[nt][mt][q] = 0.f;

  const int ar = t >> 3;                // 32 A-rows, 8 threads/row
  const int cb = (t & 7) * 16;          // 16 contiguous cols/thread
  const int nd0 = nBase + ar;
  const int nn = nd0 < Nn ? nd0 : Nn - 1;

  // ---- stage h half (full width, hi+lo)
  {
    const float* p = &h[(size_t)nn * 128 + cb];
#pragma unroll
    for (int jj = 0; jj < 2; jj++) {
      float4 u0 = *(const float4*)(p + jj * 8);
      float4 u1 = *(const float4*)(p + jj * 8 + 4);
      float xs[8] = {u0.x, u0.y, u0.z, u0.w, u1.x, u1.y, u1.z, u1.w};
      bf16x8 vh, vl;
#pragma unroll
      for (int j = 0; j < 8; j++) {
        short hi = f2bf(xs[j]);
        vh[j] = hi; vl[j] = f2bf(xs[j] - bf2f(hi));
      }
      *(bf16x8*)&Ah[ar * HTT + cb + jj * 8] = vh;
      *(bf16x8*)&Al[ar * HTT + cb + jj * 8] = vl;
    }
  }
  __syncthreads();

  // ---- MFMA k=0..127 (h part): 3-term split-bf16, B direct from global
#pragma unroll
  for (int c = 0; c < 4; c++) {
    const int k0 = c * 32;
    bf16x8 bh0 = *(const bf16x8*)&Wth[(size_t)(wave * 32 + ml) * 256 + k0 + ko];
    bf16x8 bl0 = *(const bf16x8*)&Wtl[(size_t)(wave * 32 + ml) * 256 + k0 + ko];
    bf16x8 bh1 = *(const bf16x8*)&Wth[(size_t)(wave * 32 + 16 + ml) * 256 + k0 + ko];
    bf16x8 bl1 = *(const bf16x8*)&Wtl[(size_t)(wave * 32 + 16 + ml) * 256 + k0 + ko];
#pragma unroll
    for (int mt = 0; mt < 2; mt++) {
      bf16x8 ah = *(const bf16x8*)&Ah[(mt * 16 + ml) * HTT + k0 + ko];
      bf16x8 al = *(const bf16x8*)&Al[(mt * 16 + ml) * HTT + k0 + ko];
      acc[0][mt] = __builtin_amdgcn_mfma_f32_16x16x32_bf16(ah, bh0, acc[0][mt], 0, 0, 0);
      acc[0][mt] = __builtin_amdgcn_mfma_f32_16x16x32_bf16(ah, bl0, acc[0][mt], 0, 0, 0);
      acc[0][mt] = __builtin_amdgcn_mfma_f32_16x16x32_bf16(al, bh0, acc[0][mt], 0, 0, 0);
      acc[1][mt] = __builtin_amdgcn_mfma_f32_16x16x32_bf16(ah, bh1, acc[1][mt], 0, 0, 0);
      acc[1][mt] = __builtin_amdgcn_mfma_f32_16x16x32_bf16(ah, bl1, acc[1][mt], 0, 0, 0);
      acc[1][mt] = __builtin_amdgcn_mfma_f32_16x16x32_bf16(al, bh1, acc[1][mt], 0, 0, 0);
    }
  }
  __syncthreads();   // Ah/Al reads done

  // ---- stage agg half (hi only, overwrites Ah)
  {
    const unsigned short* pa = &aggbf[(size_t)nn * 128 + cb];
#pragma unroll
    for (int jj = 0; jj < 2; jj++)
      *(bf16x8*)&Ah[ar * HTT + cb + jj * 8] = *(const bf16x8*)(pa + jj * 8);
  }
  __syncthreads();

  // ---- MFMA k=128..255 (agg part): 2-term
#pragma unroll
  for (int c = 4; c < 8; c++) {
    const int k0 = c * 32, ka = (c - 4) * 32;
    bf16x8 bh0 = *(const bf16x8*)&Wth[(size_t)(wave * 32 + ml) * 256 + k0 + ko];
    bf16x8 bl0 = *(const bf16x8*)&Wtl[(size_t)(wave * 32 + ml) * 256 + k0 + ko];
    bf16x8 bh1 = *(const bf16x8*)&Wth[(size_t)(wave * 32 + 16 + ml) * 256 + k0 + ko];
    bf16x8 bl1 = *(const bf16x8*)&Wtl[(size_t)(wave * 32 + 16 + ml) * 256 + k0 + ko];
#pragma unroll
    for (int mt = 0; mt < 2; mt++) {
      bf16x8 ah = *(const bf16x8*)&Ah[(mt * 16 + ml) * HTT + ka + ko];
      acc[0][mt] = __builtin_amdgcn_mfma_f32_16x16x32_bf16(ah, bh0, acc[0][mt], 0, 0, 0);
      acc[0][mt] = __builtin_amdgcn_mfma_f32_16x16x32_bf16(ah, bl0, acc[0][mt], 0, 0, 0);
      acc[1][mt] = __builtin_amdgcn_mfma_f32_16x16x32_bf16(ah, bh1, acc[1][mt], 0, 0, 0);
      acc[1][mt] = __builtin_amdgcn_mfma_f32_16x16x32_bf16(ah, bl1, acc[1][mt], 0, 0, 0);
    }
  }
  __syncthreads();   // all A reads complete before hnT overwrites ms

  // ---- epilogue: hn + h write + hnT + fused group-sum
#pragma unroll
  for (int nt = 0; nt < 2; nt++) {
    const int ch = wave * 32 + nt * 16 + ml;
#pragma unroll
    for (int mt = 0; mt < 2; mt++) {
      int lrb = mt * 16 + quad * 4;
      int rbase = nBase + lrb;
      float runv = 0.f;
      int curb = -1;
#pragma unroll
      for (int q = 0; q < 4; q++) {
        int nd = rbase + q;
        short hv = 0;
        if (nd < Nn) {
          int bi = batch[nd];
          float u = fmaxf(acc[nt][mt][q] + gbs[bi * 128 + ch], 0.f);
          float hn = h[(size_t)nd * 128 + ch] + u;
          h[(size_t)nd * 128 + ch] = hn;
          hv = f2bf(hn);
          if (bi != curb) {
            if (curb >= 0) atomicAdd(&ls[curb * 128 + ch], runv);
            curb = bi;
            runv = 0.f;
          }
          runv += hn;
        }
        hnT[(lrb + q) * HTT + ch] = hv;
      }
      if (curb >= 0) atomicAdd(&ls[curb * 128 + ch], runv);
    }
  }
  __syncthreads();   // hnT + ls complete
#pragma unroll
  for (int q = 0; q < 4; q++) {
    int idx = t + q * 256;
    float v = ls[idx];
    if (v != 0.f) atomicAdd(&gsum_out[idx], v);
  }

  // ---- phase C: proj of the NEW h (skipped on last round)
  if (doproj) {
#pragma unroll 1
    for (int y = 0; y < 2; y++) {
      f32x4 pacc[2][2];
#pragma unroll
      for (int nt = 0; nt < 2; nt++)
#pragma unroll
        for (int mt = 0; mt < 2; mt++)
#pragma unroll
          for (int q = 0; q < 4; q++) pacc[nt][mt][q] = 0.f;
#pragma unroll
      for (int c = 0; c < 4; c++) {
        const bf16x8 b0 = *(const bf16x8*)&Wmth[(size_t)(y * 128 + wave * 32 + ml) * 128 + c * 32 + ko];
        const bf16x8 b1 = *(const bf16x8*)&Wmth[(size_t)(y * 128 + wave * 32 + 16 + ml) * 128 + c * 32 + ko];
#pragma unroll
        for (int mt = 0; mt < 2; mt++) {
          bf16x8 ah = *(const bf16x8*)&hnT[(mt * 16 + ml) * HTT + c * 32 + ko];
          pacc[0][mt] = __builtin_amdgcn_mfma_f32_16x16x32_bf16(ah, b0, pacc[0][mt], 0, 0, 0);
          pacc[1][mt] = __builtin_amdgcn_mfma_f32_16x16x32_bf16(ah, b1, pacc[1][mt], 0, 0, 0);
        }
      }
      if (y == 0) {
#pragma unroll
        for (int nt = 0; nt < 2; nt++) {
          const int ch = wave * 32 + nt * 16 + ml;
#pragma unroll
          for (int mt = 0; mt < 2; mt++) {
#pragma unroll
            for (int q = 0; q < 4; q++) {
              int nd = nBase + mt * 16 + quad * 4 + q;
              if (nd < Nn) {
                int pk = __builtin_amdgcn_cvt_pk_fp8_f32(pacc[nt][mt][q], pacc[nt][mt][q], 0, false);
                hs8[(size_t)nd * 128 + ch] = (unsigned char)(pk & 0xff);
              }
            }
          }
        }
      } else {
#pragma unroll
        for (int nt = 0; nt < 2; nt++) {
          const int ch = wave * 32 + nt * 16 + ml;
#pragma unroll
          for (int mt = 0; mt < 2; mt++) {
#pragma unroll
            for (int q = 0; q < 4; q++) {
              int nd = nBase + mt * 16 + quad * 4 + q;
              if (nd < Nn) hdbf[(size_t)nd * 128 + ch] = (unsigned short)f2bf(pacc[nt][mt][q]);
            }
          }
        }
      }
    }
  }
}

// ---------------------------------------------------------------- kwv (MFMA bf16) + fused decode
__global__ __launch_bounds__(256) void kwv_kernel(
    const float* __restrict__ h, const float* __restrict__ pos,
    const float* __restrict__ Fm, const float* __restrict__ Wd,
    const float* __restrict__ bd, float* __restrict__ partial,
    float* __restrict__ ksum, float* __restrict__ out) {
  __shared__ float h_s[32 * HP];     // fp32 tile for decode
  __shared__ short nkT[128 * KS];    // A: nkT[m][k]
  __shared__ short hT[128 * KS];     // B: hT[n][k]
  __shared__ float wd[512];
  __shared__ float ksum_s[128];
  __shared__ float dsum[256];
  const int t = threadIdx.x;
  const int hr = t >> 3;
  const int hc = (t & 7) * 16;
  const int fg = (t & 7) * 8;
  const int wave = t >> 6, lane = t & 63;
  const int ml = lane & 15, quad = lane >> 4;
  const int ko = quad * 8;
  if (t < 128) { *(float4*)&wd[t * 4] = *(const float4*)&Wd[t * 4]; ksum_s[t] = 0.f; }
  const float bdv = bd[t & 3];
  const int dn = (t & 127) >> 2, dno = t & 3;     // decode output (node-in-tile, out)
  const int dk0 = (t >> 7) * 64;                  // decode k half
  f32x4 acc[2][8];
#pragma unroll
  for (int nt = 0; nt < 2; nt++)
#pragma unroll
    for (int mt = 0; mt < 8; mt++)
#pragma unroll
      for (int q = 0; q < 4; q++) acc[nt][mt][q] = 0.f;
  float klc[8], kls[8];
#pragma unroll
  for (int f = 0; f < 8; f++) { klc[f] = 0.f; kls[f] = 0.f; }

  int ptile = -1;
  const int nTiles = (Nn + 31) / 32;  // 1563
  for (int tile = blockIdx.x; tile < nTiles; tile += gridDim.x) {
    const int gh = tile * 32 + hr;
    float4 hv0 = {0.f, 0.f, 0.f, 0.f}, hv1 = hv0, hv2 = hv0, hv3 = hv0;
    float cbuf[8], sbuf[8];
    if (gh < Nn) {
      const float* hp = &h[(size_t)gh * 128 + hc];
      hv0 = *(const float4*)(hp + 0);
      hv1 = *(const float4*)(hp + 4);
      hv2 = *(const float4*)(hp + 8);
      hv3 = *(const float4*)(hp + 12);
      const float px = pos[gh * 2 + 0], py = pos[gh * 2 + 1];
#pragma unroll
      for (int f = 0; f < 8; f++) {
        float p = px * Fm[fg + f] + py * Fm[64 + fg + f];
        cbuf[f] = cosf(p) * 0.125f;
        sbuf[f] = sinf(p) * 0.125f;
      }
    } else {
#pragma unroll
      for (int f = 0; f < 8; f++) { cbuf[f] = 0.f; sbuf[f] = 0.f; }
    }
    float xs[16] = {hv0.x,hv0.y,hv0.z,hv0.w, hv1.x,hv1.y,hv1.z,hv1.w,
                    hv2.x,hv2.y,hv2.z,hv2.w, hv3.x,hv3.y,hv3.z,hv3.w};
    __syncthreads();  // prev tile's LDS reads & dsum writes done
    if (ptile >= 0 && t < 128) {
      int gn = ptile * 32 + dn;
      if (gn < Nn) out[4 + (size_t)gn * 4 + dno] = dsum[t] + dsum[t + 128] + bdv;
    }
    *(float4*)&h_s[hr * HP + hc + 0]  = hv0;
    *(float4*)&h_s[hr * HP + hc + 4]  = hv1;
    *(float4*)&h_s[hr * HP + hc + 8]  = hv2;
    *(float4*)&h_s[hr * HP + hc + 12] = hv3;
#pragma unroll
    for (int i = 0; i < 16; i++) hT[(hc + i) * KS + hr] = f2bf(xs[i]);
#pragma unroll
    for (int f = 0; f < 8; f++) {
      nkT[(fg + f) * KS + hr] = f2bf(cbuf[f]);
      nkT[(64 + fg + f) * KS + hr] = f2bf(sbuf[f]);
      klc[f] += cbuf[f];
      kls[f] += sbuf[f];
    }
    __syncthreads();
#pragma unroll
    for (int mt = 0; mt < 8; mt++) {
      bf16x8 ah = *(const bf16x8*)&nkT[(mt * 16 + ml) * KS + ko];
#pragma unroll
      for (int nt = 0; nt < 2; nt++) {
        bf16x8 bh = *(const bf16x8*)&hT[(wave * 32 + nt * 16 + ml) * KS + ko];
        acc[nt][mt] = __builtin_amdgcn_mfma_f32_16x16x32_bf16(ah, bh, acc[nt][mt], 0, 0, 0);
      }
    }
    {  // decode partial: 64-deep half-loop on all 256 threads
      float s = 0.f;
#pragma unroll 4
      for (int kk = dk0; kk < dk0 + 64; kk++) {
        int k = (kk + dn) & 127;
        s = fmaf(h_s[dn * HP + k], wd[k * 4 + dno], s);
      }
      dsum[t] = s;
    }
    ptile = tile;
  }
  __syncthreads();
  if (ptile >= 0 && t < 128) {  // drain last tile
    int gn = ptile * 32 + dn;
    if (gn < Nn) out[4 + (size_t)gn * 4 + dno] = dsum[t] + dsum[t + 128] + bdv;
  }
  float* pb = &partial[(size_t)blockIdx.x * 16384];
#pragma unroll
  for (int nt = 0; nt < 2; nt++) {
    const int col = wave * 32 + nt * 16 + ml;
#pragma unroll
    for (int mt = 0; mt < 8; mt++) {
#pragma unroll
      for (int q = 0; q < 4; q++) {
        int row = mt * 16 + quad * 4 + q;
        pb[row * 128 + col] = acc[nt][mt][q];
      }
    }
  }
#pragma unroll
  for (int f = 0; f < 8; f++) {
    atomicAdd(&ksum_s[fg + f], klc[f]);
    atomicAdd(&ksum_s[64 + fg + f], kls[f]);
  }
  __syncthreads();
  if (t < 128) atomicAdd(&ksum[t], ksum_s[t]);
}

__global__ __launch_bounds__(256) void kwv_reduce(const float* __restrict__ partial,
                                                  float* __restrict__ kwv) {
  int idx = blockIdx.x * 256 + threadIdx.x;
  float s = 0.f;
  for (int b = 0; b < KWVB; b++) s += partial[(size_t)b * 16384 + idx];
  kwv[idx] = s;
}

// ---------------------------------------------------------------- final sampling head
__global__ __launch_bounds__(128) void final_kernel(
    const float* __restrict__ sp, const float* __restrict__ Fm,
    const float* __restrict__ kwv, const float* __restrict__ vs,
    const float* __restrict__ ksum, const float* __restrict__ Wd,
    const float* __restrict__ bd, float* __restrict__ out) {
  __shared__ float nq_s[128];
  __shared__ float red[2];
  __shared__ float redU[8];
  int t = threadIdx.x;
  int jj = t & 63;
  float p = sp[0] * Fm[jj] + sp[1] * Fm[64 + jj];
  nq_s[t] = ((t < 64) ? cosf(p) : sinf(p)) * 0.125f;  // ||q||=sqrt(0.5) exact
  __syncthreads();
  float num = 0.f;
#pragma unroll
  for (int g = 0; g < Bb; g++) num += vs[g * 128 + t];
  for (int k = 0; k < 128; k++) num = fmaf(nq_s[k], kwv[k * 128 + t], num);
  float dp = nq_s[t] * ksum[t];
#pragma unroll
  for (int off = 32; off > 0; off >>= 1) dp += __shfl_down(dp, off);
  if ((t & 63) == 0) red[t >> 6] = dp;
  __syncthreads();
  float den = (float)Nn + red[0] + red[1];
  float e = num / den;
  float u[4];
#pragma unroll
  for (int o = 0; o < 4; o++) u[o] = e * Wd[t * 4 + o];
#pragma unroll
  for (int off = 32; off > 0; off >>= 1) {
#pragma unroll
    for (int o = 0; o < 4; o++) u[o] += __shfl_down(u[o], off);
  }
  if ((t & 63) == 0) {
#pragma unroll
    for (int o = 0; o < 4; o++) redU[(t >> 6) * 4 + o] = u[o];
  }
  __syncthreads();
  if (t < 4) out[t] = redU[t] + redU[4 + t] + bd[t];
}

// ---------------------------------------------------------------- launcher
extern "C" void kernel_launch(void* const* d_in, const int* in_sizes, int n_in,
                              void* d_out, int out_size, void* d_ws, size_t ws_size,
                              hipStream_t stream) {
  const float* x    = (const float*)d_in[0];
  const float* xm   = (const float*)d_in[1];
  const int*   ei   = (const int*)d_in[2];
  const float* ea   = (const float*)d_in[3];
  const float* pos  = (const float*)d_in[4];
  const int*   batch= (const int*)d_in[5];
  const float* sp   = (const float*)d_in[6];
  const float* Fm   = (const float*)d_in[7];
  const float* Wenc = (const float*)d_in[8];
  const float* benc = (const float*)d_in[9];
  const float* Wmsg = (const float*)d_in[10];
  const float* bmsg = (const float*)d_in[11];
  const float* Wupd = (const float*)d_in[12];
  const float* bupd = (const float*)d_in[13];
  const float* Wdec = (const float*)d_in[14];
  const float* bdec = (const float*)d_in[15];
  float* out = (float*)d_out;

  float* ws     = (float*)d_ws;
  float* h      = ws;                              // N*128
  float* agg    = h + (size_t)Nn * 128;            // region: aggbf (12.8MB); kwv partials span
  float* aux    = agg + (size_t)Nn * 128;          // region: hs8 (6.4MB) + hdbf (12.8MB)
  float* invdeg = aux + (size_t)Nn * 128;          // N
  // ---- zeroed region (6612 x 4B, one memset) ----
  float* gsum   = invdeg + Nn;                     // 1024
  float* gcnt   = gsum + 1024;                     // 8
  float* bcsum  = gcnt + 8;                        // 1024
  float* bccnt  = bcsum + 1024;                    // 8
  float* gsumR  = bccnt + 8;                       // 4*1024
  float* vsum   = gsumR + 4096;                    // 128 (unused)
  float* ksum   = vsum + 128;                      // 128
  int*   bktcnt = (int*)(ksum + 128);              // 196
  // ---- end zeroed region ----
  float* gbst   = (float*)(bktcnt + 196);          // 1024
  float* gbuf   = gbst + 1024;                     // 4*1024
  float* kwv    = gbuf + 4096;                     // 16384
  int2*  rec    = (int2*)(kwv + 16384);            // E (packed 8B, CSR order)
  int*   cnt    = (int*)(rec + Ee);                // N
  int*   rowptr = cnt + Nn;                        // N+1
  int*   bsum   = rowptr + Nn + 1;                 // 256
  int*   boff   = bsum + 256;                      // 256
  int*   bktbase= boff + 256;                      // 197
  int*   bktcur = bktbase + 197;                   // 196
  short* wmt_h  = (short*)(bktcur + 196);          // 2*128*128
  short* wmt_l  = wmt_h + 32768;
  short* wut_h  = wmt_l + 32768;                   // 128*256
  short* wut_l  = wut_h + 32768;
  int2*  recA   = (int2*)(wut_l + 32768);          // E (bucket-partitioned staging)
  unsigned char* dlo = (unsigned char*)(recA + Ee);// E

  unsigned short* aggbf = (unsigned short*)agg;                     // 12.8 MB
  unsigned char*  hs8   = (unsigned char*)aux;                      // 6.4 MB
  unsigned short* hdbf  = (unsigned short*)(hs8 + (size_t)Nn * 128);// 12.8 MB

  hipMemsetAsync(gsum, 0, 6612 * 4, stream);

  // CSR build (bkt_cnt also performs the one-shot weight split)
  bkt_cnt<<<P1B, 256, 0, stream>>>(ei, bktcnt, Wmsg, Wupd,
                                   wmt_h, wmt_l, wut_h, wut_l);
  bkt_scan<<<1, 256, 0, stream>>>(bktcnt, bktbase, bktcur);
  bkt_part<<<P1B, 256, 0, stream>>>(ei, ea, bktcur, recA, dlo);
  dst_cnt_bsum<<<NBK, 256, 0, stream>>>(bktbase, dlo, cnt, bsum);
  scan_top_kernel<<<1, 256, 0, stream>>>(bsum, boff);
  apply_fin<<<NBK, 256, 0, stream>>>(cnt, boff, bktbase, recA, dlo,
                                     rowptr, invdeg, rec);

  const int nb128 = (Nn + 127) / 128;  // 391
  const int nb32  = (Nn + 31) / 32;    // 1563
  encode_seg<<<nb128, 256, 0, stream>>>(x, xm, batch, Wenc, benc, h,
                                        gsum, gcnt, bcsum, bccnt);

  // round 0 proj (standalone; blocks 0..7 compute gbst + gb_0)
  proj_mfma<<<nb32, 256, 0, stream>>>(h, wmt_h, hs8, hdbf,
                                      bcsum, bccnt, bupd, Wupd, gbst,
                                      gsum, gcnt, gbuf);

  for (int r = 0; r < ROUNDS; r++) {
    // agg blocks 0..7 compute gb_r for r>=1 (updg_{r-1} completed -> gsumR ready)
    agg_kernel<<<(Nn + 7) / 8, 256, 0, stream>>>(
        hs8, hdbf, aggbf, rec, rowptr, invdeg, Wmsg, bmsg,
        Wupd, gbst,
        (r == 0) ? gsum : (gsumR + (size_t)(r - 1) * 1024), gcnt,
        gbuf + (size_t)r * 1024, (r >= 1) ? 1 : 0);
    updg_proj<<<nb32, 256, 0, stream>>>(
        h, aggbf, batch, wut_h, wut_l,
        gbuf + (size_t)r * 1024, gsumR + (size_t)r * 1024,
        wmt_h, hs8, hdbf, (r < ROUNDS - 1) ? 1 : 0);
  }

  // kwv partials alias the (now free) agg+aux regions: 512*64KB = 33.5 MB < 51.2 MB
  kwv_kernel<<<KWVB, 256, 0, stream>>>(h, pos, Fm, Wdec, bdec, agg, ksum, out);
  kwv_reduce<<<64, 256, 0, stream>>>(agg, kwv);
  final_kernel<<<1, 128, 0, stream>>>(sp, Fm, kwv, gsumR + 3 * 1024, ksum,
                                      Wdec, bdec, out);
}

// Round 10
// 596.510 us; speedup vs baseline: 1.0770x; 1.0770x over previous
//
#include <hip/hip_runtime.h>
#include <math.h>

#define Nn 50000
#define Ee 800000
#define Bb 8
#define ROUNDS 4
#define KWVB 512            // kwv partial blocks (2/CU)
#define SCB 196             // scan blocks (196*256 = 50176 >= Nn)
#define AP 40               // MFMA LDS row stride in shorts (32 k + 8 pad)
#define HP 132              // kwv fp32 h_s row stride (128 + 4 pad)
#define KS 40               // kwv bf16 transposed row stride in shorts
#define HTT 136             // hnT bf16 full-row stride in shorts (128 + 8 pad)
#define NBK 196             // dst buckets (dst >> 8)
#define P1B 391             // partition blocks
#define CHUNK 2047          // edges per partition block (391*2047 >= Ee)

typedef __attribute__((ext_vector_type(8))) short bf16x8;
typedef __attribute__((ext_vector_type(4))) float f32x4;

__device__ inline short f2bf(float f) {
  union { float f; unsigned u; } v; v.f = f;
  unsigned r = v.u + 0x7fff + ((v.u >> 16) & 1);  // RNE
  return (short)(r >> 16);
}
__device__ inline float bf2f(short s) {
  union { float f; unsigned u; } v; v.u = ((unsigned)(unsigned short)s) << 16;
  return v.f;
}

// ---------------------------------------------------------------- D1: CSR bucket-count + weight split  ||  encode + segmean
__global__ __launch_bounds__(256) void csr_enc(
    const int* __restrict__ ei, int* __restrict__ bktcnt,
    const float* __restrict__ Wm, const float* __restrict__ Wu,
    short* __restrict__ Wmt_h, short* __restrict__ Wmt_l,
    short* __restrict__ Wut_h, short* __restrict__ Wut_l,
    const float* __restrict__ x, const float* __restrict__ xm,
    const int* __restrict__ batch, const float* __restrict__ W,
    const float* __restrict__ b, float* __restrict__ h,
    float* __restrict__ gsum, float* __restrict__ gcnt,
    float* __restrict__ bcsum, float* __restrict__ bccnt) {
  __shared__ int hist[NBK];
  __shared__ float xs5[128 * 5];
  __shared__ float xm3[128 * 3];
  __shared__ float ls[Bb * 128];
  __shared__ float lb[Bb * 128];
  __shared__ float lc[Bb], lbc[Bb];
  const int t = threadIdx.x;
  if (blockIdx.x < P1B) {
    // ---- CSR count + split_w
    int idx = blockIdx.x * 256 + t;
    if (idx < 32768) {
      int k = idx & 127, n = (idx >> 7) & 127, y = idx >> 14;
      float w = Wm[(size_t)(y * 128 + k) * 128 + n];
      short hi = f2bf(w);
      Wmt_h[idx] = hi;
      Wmt_l[idx] = f2bf(w - bf2f(hi));
    } else if (idx < 65536) {
      int j = idx - 32768;
      int k = j & 255, n = j >> 8;
      float w = Wu[(size_t)k * 128 + n];
      short hi = f2bf(w);
      Wut_h[j] = hi;
      Wut_l[j] = f2bf(w - bf2f(hi));
    }
    for (int q = t; q < NBK; q += 256) hist[q] = 0;
    __syncthreads();
    int base = blockIdx.x * CHUNK;
    int end = base + CHUNK < Ee ? base + CHUNK : Ee;
    for (int e = base + t; e < end; e += 256) atomicAdd(&hist[ei[Ee + e] >> 8], 1);
    __syncthreads();
    for (int q = t; q < NBK; q += 256)
      if (hist[q]) atomicAdd(&bktcnt[q], hist[q]);
    return;
  }
  // ---- encode + fused segmean
  const int nBase = (blockIdx.x - P1B) * 128;
  const int j = t & 127, half = t >> 7;
  const int base5 = nBase * 5, base3 = nBase * 3;
  for (int q = t; q < 640; q += 256) xs5[q] = (base5 + q < Nn * 5) ? x[base5 + q] : 0.f;
  for (int q = t; q < 384; q += 256) xm3[q] = (base3 + q < Nn * 3) ? xm[base3 + q] : 0.f;
  for (int q = t; q < Bb * 128; q += 256) { ls[q] = 0.f; lb[q] = 0.f; }
  if (t < Bb) { lc[t] = 0.f; lbc[t] = 0.f; }
  float Wcol[8];
#pragma unroll
  for (int k = 0; k < 8; k++) Wcol[k] = W[k * 128 + j];
  const float bj = b[j];
  __syncthreads();
  int curb = -1;
  float runh = 0.f, runb = 0.f, runc = 0.f, runbc = 0.f;
  for (int kk = 0; kk < 64; kk++) {
    int i = nBase + kk * 2 + half;
    if (i >= Nn) break;
    int li = i - nBase;
    float acc = bj;
#pragma unroll
    for (int k = 0; k < 5; k++) acc = fmaf(xs5[li * 5 + k], Wcol[k], acc);
#pragma unroll
    for (int k = 0; k < 3; k++) acc = fmaf(xm3[li * 3 + k], Wcol[5 + k], acc);
    float v = fmaxf(acc, 0.f);
    h[(size_t)i * 128 + j] = v;
    float bc = xm3[li * 3 + 2];
    int g = batch[i];
    if (g != curb) {
      if (curb >= 0) {
        atomicAdd(&ls[curb * 128 + j], runh);
        atomicAdd(&lb[curb * 128 + j], runb);
        if (j == 0) { atomicAdd(&lc[curb], runc); atomicAdd(&lbc[curb], runbc); }
      }
      curb = g; runh = runb = runc = runbc = 0.f;
    }
    runh += v; runb += v * bc;
    if (j == 0) { runc += 1.f; runbc += bc; }
  }
  if (curb >= 0) {
    atomicAdd(&ls[curb * 128 + j], runh);
    atomicAdd(&lb[curb * 128 + j], runb);
    if (j == 0) { atomicAdd(&lc[curb], runc); atomicAdd(&lbc[curb], runbc); }
  }
  __syncthreads();
  for (int q = t; q < Bb * 128; q += 256) {
    float a = ls[q], c = lb[q];
    if (a != 0.f) atomicAdd(&gsum[q], a);
    if (c != 0.f) atomicAdd(&bcsum[q], c);
  }
  if (t < Bb) { atomicAdd(&gcnt[t], lc[t]); atomicAdd(&bccnt[t], lbc[t]); }
}

// ---------------------------------------------------------------- D2: bkt_part (local scan)  ||  round-0 proj (+gbst/gb0)
__global__ __launch_bounds__(256) void part_proj(
    const int* __restrict__ ei, const float* __restrict__ ea,
    const int* __restrict__ bktcnt, int* __restrict__ bktcur,
    int2* __restrict__ recA, unsigned char* __restrict__ dlo,
    const float* __restrict__ h, const short* __restrict__ Wth,
    unsigned char* __restrict__ hs8, unsigned short* __restrict__ hdbf,
    const float* __restrict__ bcsum, const float* __restrict__ bccnt,
    const float* __restrict__ bu, const float* __restrict__ Wu,
    float* __restrict__ gbst, const float* __restrict__ gsum_in,
    const float* __restrict__ gcnt, float* __restrict__ gb_out) {
  __shared__ int hist[NBK], lbase[NBK], lcur[NBK], bb[NBK], sS[256];
  __shared__ short Ah_s[64 * AP];
  __shared__ short Bh_s[256 * AP];
  const int t = threadIdx.x;
  if (blockIdx.x < P1B) {
    // local exclusive scan of bktcnt -> bb
    int v = (t < NBK) ? bktcnt[t] : 0;
    sS[t] = v;
    __syncthreads();
    for (int off = 1; off < 256; off <<= 1) {
      int xo = (t >= off) ? sS[t - off] : 0;
      __syncthreads();
      sS[t] += xo;
      __syncthreads();
    }
    if (t < NBK) bb[t] = sS[t] - v;
    for (int q = t; q < NBK; q += 256) hist[q] = 0;
    __syncthreads();
    int base = blockIdx.x * CHUNK;
    int end = base + CHUNK < Ee ? base + CHUNK : Ee;
    for (int e = base + t; e < end; e += 256) atomicAdd(&hist[ei[Ee + e] >> 8], 1);
    __syncthreads();
    for (int q = t; q < NBK; q += 256) {
      int c = hist[q];
      lbase[q] = c ? (bb[q] + atomicAdd(&bktcur[q], c)) : 0;
      lcur[q] = 0;
    }
    __syncthreads();
    for (int e = base + t; e < end; e += 256) {
      int d = ei[Ee + e];
      int bk = d >> 8;
      int p = lbase[bk] + atomicAdd(&lcur[bk], 1);
      unsigned r0 = (unsigned)ei[e] |
                    ((unsigned)(unsigned short)f2bf(ea[3 * (size_t)e + 0]) << 16);
      unsigned r1 = (unsigned)(unsigned short)f2bf(ea[3 * (size_t)e + 1]) |
                    ((unsigned)(unsigned short)f2bf(ea[3 * (size_t)e + 2]) << 16);
      recA[p] = make_int2((int)r0, (int)r1);
      dlo[p] = (unsigned char)(d & 255);
    }
    return;
  }
  // ---- proj tile
  const int pbid = blockIdx.x - P1B;
  const int nBase = pbid * 64;
  const int wave = t >> 6, lane = t & 63;
  const int ml = lane & 15, quad = lane >> 4;
  const int ko = quad * 8;

  // gb prologue (proj blocks 0..7; Bh_s reused as float scratch, barrier-fenced)
  if (pbid < Bb) {
    float* xgs = (float*)Bh_s;
    const int g = pbid;
    if (t < 128) xgs[t] = bcsum[g * 128 + t] / fmaxf(bccnt[g], 1.f);
    __syncthreads();
    if (t < 128) {
      float a = bu[t];
#pragma unroll 4
      for (int k = 0; k < 128; k++) a = fmaf(xgs[k], Wu[(size_t)(384 + k) * 128 + t], a);
      gbst[g * 128 + t] = a;
    }
    __syncthreads();
    if (t < 128) xgs[t] = gsum_in[g * 128 + t] / fmaxf(gcnt[g], 1.f);
    __syncthreads();
    if (t < 128) {
      float a = gbst[g * 128 + t];
#pragma unroll 4
      for (int k = 0; k < 128; k++) a = fmaf(xgs[k], Wu[(size_t)(256 + k) * 128 + t], a);
      gb_out[g * 128 + t] = a;
    }
  }

  f32x4 acc[4][4];   // [y*2+nt][mt]
#pragma unroll
  for (int yn = 0; yn < 4; yn++)
#pragma unroll
    for (int mt = 0; mt < 4; mt++)
#pragma unroll
      for (int q = 0; q < 4; q++) acc[yn][mt][q] = 0.f;

  const int arow = t >> 2;              // 64 A-rows, 4 threads/row
  const int kq = (t & 3) * 8;           // 8-col slice of the 32-col chunk
  const int nd0 = nBase + arow;
  const int nn = nd0 < Nn ? nd0 : Nn - 1;

  for (int c = 0; c < 4; c++) {
    const int k0 = c * 32;
    const float* p = &h[(size_t)nn * 128 + k0 + kq];
    float4 u0 = *(const float4*)(p + 0);
    float4 u1 = *(const float4*)(p + 4);
    // B: thread t stages row t (of 256) for this 32-col chunk
    const bf16x8 w0 = *(const bf16x8*)&Wth[(size_t)t * 128 + k0];
    const bf16x8 w1 = *(const bf16x8*)&Wth[(size_t)t * 128 + k0 + 8];
    const bf16x8 w2 = *(const bf16x8*)&Wth[(size_t)t * 128 + k0 + 16];
    const bf16x8 w3 = *(const bf16x8*)&Wth[(size_t)t * 128 + k0 + 24];
    float xs[8] = {u0.x, u0.y, u0.z, u0.w, u1.x, u1.y, u1.z, u1.w};
    bf16x8 vh0;
#pragma unroll
    for (int j = 0; j < 8; j++) vh0[j] = f2bf(xs[j]);
    __syncthreads();
    *(bf16x8*)&Ah_s[arow * AP + kq] = vh0;
    *(bf16x8*)&Bh_s[t * AP + 0] = w0;
    *(bf16x8*)&Bh_s[t * AP + 8] = w1;
    *(bf16x8*)&Bh_s[t * AP + 16] = w2;
    *(bf16x8*)&Bh_s[t * AP + 24] = w3;
    __syncthreads();
#pragma unroll
    for (int mt = 0; mt < 4; mt++) {
      const int ar = (mt * 16 + ml) * AP + ko;
      bf16x8 ah = *(const bf16x8*)&Ah_s[ar];
#pragma unroll
      for (int y = 0; y < 2; y++) {
#pragma unroll
        for (int nt = 0; nt < 2; nt++) {
          const int br = (y * 128 + wave * 32 + nt * 16 + ml) * AP + ko;
          bf16x8 bh = *(const bf16x8*)&Bh_s[br];
          acc[y * 2 + nt][mt] = __builtin_amdgcn_mfma_f32_16x16x32_bf16(ah, bh, acc[y * 2 + nt][mt], 0, 0, 0);
        }
      }
    }
  }
#pragma unroll
  for (int nt = 0; nt < 2; nt++) {
    const int ch = wave * 32 + nt * 16 + ml;
#pragma unroll
    for (int mt = 0; mt < 4; mt++) {
#pragma unroll
      for (int q = 0; q < 4; q++) {
        int nd = nBase + mt * 16 + quad * 4 + q;
        if (nd < Nn) {
          int pk = __builtin_amdgcn_cvt_pk_fp8_f32(acc[nt][mt][q], acc[nt][mt][q], 0, false);
          hs8[(size_t)nd * 128 + ch] = (unsigned char)(pk & 0xff);
          hdbf[(size_t)nd * 128 + ch] = (unsigned short)f2bf(acc[2 + nt][mt][q]);
        }
      }
    }
  }
}

// ---------------------------------------------------------------- dst_cnt + per-block sum (bucket ranges from local scan)
__global__ __launch_bounds__(256) void dst_cnt_bsum(
    const int* __restrict__ bktcnt, const unsigned char* __restrict__ dlo,
    int* __restrict__ cnt, int* __restrict__ bsum) {
  __shared__ int s[256];
  __shared__ int hh[256];
  __shared__ int wsum[4];
  int t = threadIdx.x;
  int b = blockIdx.x;
  int vv = (t < NBK) ? bktcnt[t] : 0;
  s[t] = vv;
  __syncthreads();
  for (int off = 1; off < 256; off <<= 1) {
    int xo = (t >= off) ? s[t - off] : 0;
    __syncthreads();
    s[t] += xo;
    __syncthreads();
  }
  int lo = (b == 0) ? 0 : s[b - 1];
  int hi = s[b];
  hh[t] = 0;
  __syncthreads();
  for (int i = lo + t; i < hi; i += 256) atomicAdd(&hh[dlo[i]], 1);
  __syncthreads();
  int d = b * 256 + t;
  int v = hh[t];
  if (d < Nn) cnt[d] = v;
#pragma unroll
  for (int off = 32; off > 0; off >>= 1) v += __shfl_down(v, off);
  if ((t & 63) == 0) wsum[t >> 6] = v;
  __syncthreads();
  if (t == 0) bsum[b] = wsum[0] + wsum[1] + wsum[2] + wsum[3];
}

// ---------------------------------------------------------------- apply (rowptr/invdeg) + scatter; scans computed locally
__global__ __launch_bounds__(256) void apply_fin(
    const int* __restrict__ cnt, const int* __restrict__ bsum,
    const int* __restrict__ bktcnt, const int2* __restrict__ recA,
    const unsigned char* __restrict__ dlo,
    int* __restrict__ rowptr, float* __restrict__ invdeg,
    int2* __restrict__ rec) {
  __shared__ int s[256];
  __shared__ int cur[256];
  int t = threadIdx.x, b = blockIdx.x;
  // scan bsum -> boffb
  int vb = (t < SCB) ? bsum[t] : 0;
  s[t] = vb;
  __syncthreads();
  for (int off = 1; off < 256; off <<= 1) {
    int xo = (t >= off) ? s[t - off] : 0;
    __syncthreads();
    s[t] += xo;
    __syncthreads();
  }
  int boffb = (b == 0) ? 0 : s[b - 1];
  __syncthreads();
  // scan bktcnt -> bucket range [lo, hi)
  int vk = (t < NBK) ? bktcnt[t] : 0;
  s[t] = vk;
  __syncthreads();
  for (int off = 1; off < 256; off <<= 1) {
    int xo = (t >= off) ? s[t - off] : 0;
    __syncthreads();
    s[t] += xo;
    __syncthreads();
  }
  int lo = (b == 0) ? 0 : s[b - 1];
  int hi = s[b];
  __syncthreads();
  // local scan of cnt -> rowptr / invdeg / cursors
  int i = b * 256 + t;
  int v = (i < Nn) ? cnt[i] : 0;
  s[t] = v;
  __syncthreads();
  for (int off = 1; off < 256; off <<= 1) {
    int xo = (t >= off) ? s[t - off] : 0;
    __syncthreads();
    s[t] += xo;
    __syncthreads();
  }
  int ex = boffb + s[t] - v;
  if (i < Nn) {
    rowptr[i] = ex;
    invdeg[i] = 1.0f / fmaxf((float)v, 1.0f);
    if (i == Nn - 1) rowptr[Nn] = ex + v;
  }
  cur[t] = ex;
  __syncthreads();
  for (int ii = lo + t; ii < hi; ii += 256) {
    int dl = dlo[ii];
    int p = atomicAdd(&cur[dl], 1);
    rec[p] = recA[ii];
  }
}

// ---------------------------------------------------------------- edge pass / aggregation (+gb for r>=1 on blocks 0..7)
__global__ __launch_bounds__(256) void agg_kernel(
    const unsigned char* __restrict__ hs8, const unsigned short* __restrict__ hdbf,
    unsigned short* __restrict__ aggbf, const int2* __restrict__ rec,
    const int* __restrict__ rowptr, const float* __restrict__ invdeg,
    const float* __restrict__ Wm, const float* __restrict__ bm,
    const float* __restrict__ Wu, const float* __restrict__ gbst,
    const float* __restrict__ gsum_in, const float* __restrict__ gcnt,
    float* __restrict__ gb_out, int dogb) {
  __shared__ float xgs[128];
  int t = threadIdx.x;
  if (dogb && blockIdx.x < Bb) {
    const int g = blockIdx.x;
    if (t < 128) xgs[t] = gsum_in[g * 128 + t] / fmaxf(gcnt[g], 1.f);
    __syncthreads();
    if (t < 128) {
      float a = gbst[g * 128 + t];
#pragma unroll 4
      for (int k = 0; k < 128; k++) a = fmaf(xgs[k], Wu[(size_t)(256 + k) * 128 + t], a);
      gb_out[g * 128 + t] = a;
    }
  }
  int hw = t >> 5, lane = t & 31;
  int v = blockIdx.x * 8 + hw;
  if (v >= Nn) return;
  int c0 = lane * 4;
  const float4 We0 = *(const float4*)&Wm[(size_t)256 * 128 + c0];
  const float4 We1 = *(const float4*)&Wm[(size_t)257 * 128 + c0];
  const float4 We2 = *(const float4*)&Wm[(size_t)258 * 128 + c0];
  const float4 b4  = *(const float4*)&bm[c0];
  const ushort4 hd4 = *(const ushort4*)&hdbf[(size_t)v * 128 + c0];
  const float bx = b4.x + bf2f((short)hd4.x), by = b4.y + bf2f((short)hd4.y),
              bz = b4.z + bf2f((short)hd4.z), bw = b4.w + bf2f((short)hd4.w);
  float ax = 0.f, ay = 0.f, az = 0.f, aw = 0.f;
  float ax2 = 0.f, ay2 = 0.f, az2 = 0.f, aw2 = 0.f;
  const int r0 = rowptr[v], r1 = rowptr[v + 1];
  int e = r0;
  for (; e + 2 <= r1; e += 2) {
    int2 q0 = rec[e], q1 = rec[e + 1];
    int s0 = q0.x & 0xffff, s1 = q1.x & 0xffff;
    unsigned hr0 = *(const unsigned*)&hs8[(size_t)s0 * 128 + c0];
    unsigned hr1 = *(const unsigned*)&hs8[(size_t)s1 * 128 + c0];
    float e00 = bf2f((short)(q0.x >> 16));
    float e01 = bf2f((short)(q0.y & 0xffff));
    float e02 = bf2f((short)(q0.y >> 16));
    float e10 = bf2f((short)(q1.x >> 16));
    float e11 = bf2f((short)(q1.y & 0xffff));
    float e12 = bf2f((short)(q1.y >> 16));
    float h0x = __builtin_amdgcn_cvt_f32_fp8(hr0, 0);
    float h0y = __builtin_amdgcn_cvt_f32_fp8(hr0, 1);
    float h0z = __builtin_amdgcn_cvt_f32_fp8(hr0, 2);
    float h0w = __builtin_amdgcn_cvt_f32_fp8(hr0, 3);
    float h1x = __builtin_amdgcn_cvt_f32_fp8(hr1, 0);
    float h1y = __builtin_amdgcn_cvt_f32_fp8(hr1, 1);
    float h1z = __builtin_amdgcn_cvt_f32_fp8(hr1, 2);
    float h1w = __builtin_amdgcn_cvt_f32_fp8(hr1, 3);
    ax += fmaxf(fmaf(e00, We0.x, fmaf(e01, We1.x, fmaf(e02, We2.x, h0x + bx))), 0.f);
    ay += fmaxf(fmaf(e00, We0.y, fmaf(e01, We1.y, fmaf(e02, We2.y, h0y + by))), 0.f);
    az += fmaxf(fmaf(e00, We0.z, fmaf(e01, We1.z, fmaf(e02, We2.z, h0z + bz))), 0.f);
    aw += fmaxf(fmaf(e00, We0.w, fmaf(e01, We1.w, fmaf(e02, We2.w, h0w + bw))), 0.f);
    ax2 += fmaxf(fmaf(e10, We0.x, fmaf(e11, We1.x, fmaf(e12, We2.x, h1x + bx))), 0.f);
    ay2 += fmaxf(fmaf(e10, We0.y, fmaf(e11, We1.y, fmaf(e12, We2.y, h1y + by))), 0.f);
    az2 += fmaxf(fmaf(e10, We0.z, fmaf(e11, We1.z, fmaf(e12, We2.z, h1z + bz))), 0.f);
    aw2 += fmaxf(fmaf(e10, We0.w, fmaf(e11, We1.w, fmaf(e12, We2.w, h1w + bw))), 0.f);
  }
  if (e < r1) {
    int2 q0 = rec[e];
    int s0 = q0.x & 0xffff;
    unsigned hr0 = *(const unsigned*)&hs8[(size_t)s0 * 128 + c0];
    float e00 = bf2f((short)(q0.x >> 16));
    float e01 = bf2f((short)(q0.y & 0xffff));
    float e02 = bf2f((short)(q0.y >> 16));
    float h0x = __builtin_amdgcn_cvt_f32_fp8(hr0, 0);
    float h0y = __builtin_amdgcn_cvt_f32_fp8(hr0, 1);
    float h0z = __builtin_amdgcn_cvt_f32_fp8(hr0, 2);
    float h0w = __builtin_amdgcn_cvt_f32_fp8(hr0, 3);
    ax += fmaxf(fmaf(e00, We0.x, fmaf(e01, We1.x, fmaf(e02, We2.x, h0x + bx))), 0.f);
    ay += fmaxf(fmaf(e00, We0.y, fmaf(e01, We1.y, fmaf(e02, We2.y, h0y + by))), 0.f);
    az += fmaxf(fmaf(e00, We0.z, fmaf(e01, We1.z, fmaf(e02, We2.z, h0z + bz))), 0.f);
    aw += fmaxf(fmaf(e00, We0.w, fmaf(e01, We1.w, fmaf(e02, We2.w, h0w + bw))), 0.f);
  }
  const float idg = invdeg[v];
  ushort4 o;
  o.x = (unsigned short)f2bf((ax + ax2) * idg);
  o.y = (unsigned short)f2bf((ay + ay2) * idg);
  o.z = (unsigned short)f2bf((az + az2) * idg);
  o.w = (unsigned short)f2bf((aw + aw2) * idg);
  *(ushort4*)&aggbf[(size_t)v * 128 + c0] = o;
}

// ---------------------------------------------------------------- fused update + proj (exact R5-measured variant):
// A staged by 4 threads/row (arow/kq), B by 2 threads/row (brow/kc).
__global__ __launch_bounds__(256) void updg_proj(
    float* __restrict__ h, const unsigned short* __restrict__ aggbf,
    const int* __restrict__ batch,
    const short* __restrict__ Wth, const short* __restrict__ Wtl,
    const float* __restrict__ gb, float* __restrict__ gsum_out,
    const short* __restrict__ Wmth, unsigned char* __restrict__ hs8,
    unsigned short* __restrict__ hdbf, int doproj) {
  __shared__ short ms[15360];   // Ah|Al|Bh|Bl (30.7 KB); hnT (17.4 KB) aliases
  __shared__ float gbs[Bb * 128];
  __shared__ float ls[Bb * 128];
  short* Ah_s = ms;                    // 64*AP = 2560
  short* Al_s = ms + 64 * AP;          // 2560
  short* Bh_s = ms + 2 * 64 * AP;      // 128*AP = 5120
  short* Bl_s = ms + 2 * 64 * AP + 128 * AP;
  short* hnT  = ms;                    // 64*HTT = 8704 shorts

  const int t = threadIdx.x;
  const int nBase = blockIdx.x * 64;
  *(float4*)&gbs[t * 4] = *(const float4*)&gb[t * 4];
#pragma unroll
  for (int q = 0; q < 4; q++) ls[t + q * 256] = 0.f;

  const int wave = t >> 6, lane = t & 63;
  const int ml = lane & 15, quad = lane >> 4;
  const int ko = quad * 8;

  f32x4 acc[2][4];
#pragma unroll
  for (int nt = 0; nt < 2; nt++)
#pragma unroll
    for (int mt = 0; mt < 4; mt++)
#pragma unroll
      for (int q = 0; q < 4; q++) acc[nt][mt][q] = 0.f;

  const int arow = t >> 2;              // 64 A-rows, 4 threads/row
  const int kq = (t & 3) * 8;
  const int brow = t >> 1;              // 128 B-rows, 2 threads/row
  const int kc = (t & 1) * 16;
  const int nd0 = nBase + arow;
  const int nn = nd0 < Nn ? nd0 : Nn - 1;

  for (int c = 0; c < 8; c++) {
    const int k0 = c * 32;
    bf16x8 vh0, vl0;
    if (c < 4) {
      const float* p = &h[(size_t)nn * 128 + k0 + kq];
      float4 u0 = *(const float4*)(p + 0);
      float4 u1 = *(const float4*)(p + 4);
      float xs[8] = {u0.x, u0.y, u0.z, u0.w, u1.x, u1.y, u1.z, u1.w};
#pragma unroll
      for (int j = 0; j < 8; j++) {
        short hi = f2bf(xs[j]);
        vh0[j] = hi; vl0[j] = f2bf(xs[j] - bf2f(hi));
      }
    } else {
      vh0 = *(const bf16x8*)&aggbf[(size_t)nn * 128 + (c - 4) * 32 + kq];
    }
    const bf16x8 gb0 = *(const bf16x8*)&Wth[(size_t)brow * 256 + k0 + kc];
    const bf16x8 gb1 = *(const bf16x8*)&Wth[(size_t)brow * 256 + k0 + kc + 8];
    const bf16x8 gl0 = *(const bf16x8*)&Wtl[(size_t)brow * 256 + k0 + kc];
    const bf16x8 gl1 = *(const bf16x8*)&Wtl[(size_t)brow * 256 + k0 + kc + 8];
    __syncthreads();
    *(bf16x8*)&Ah_s[arow * AP + kq] = vh0;
    if (c < 4) *(bf16x8*)&Al_s[arow * AP + kq] = vl0;
    *(bf16x8*)&Bh_s[brow * AP + kc] = gb0;
    *(bf16x8*)&Bh_s[brow * AP + kc + 8] = gb1;
    *(bf16x8*)&Bl_s[brow * AP + kc] = gl0;
    *(bf16x8*)&Bl_s[brow * AP + kc + 8] = gl1;
    __syncthreads();
    if (c < 4) {
#pragma unroll
      for (int mt = 0; mt < 4; mt++) {
        const int ar = (mt * 16 + ml) * AP + ko;
        bf16x8 ah = *(const bf16x8*)&Ah_s[ar];
        bf16x8 al = *(const bf16x8*)&Al_s[ar];
#pragma unroll
        for (int nt = 0; nt < 2; nt++) {
          const int br = (wave * 32 + nt * 16 + ml) * AP + ko;
          bf16x8 bh = *(const bf16x8*)&Bh_s[br];
          bf16x8 bl = *(const bf16x8*)&Bl_s[br];
          acc[nt][mt] = __builtin_amdgcn_mfma_f32_16x16x32_bf16(ah, bh, acc[nt][mt], 0, 0, 0);
          acc[nt][mt] = __builtin_amdgcn_mfma_f32_16x16x32_bf16(ah, bl, acc[nt][mt], 0, 0, 0);
          acc[nt][mt] = __builtin_amdgcn_mfma_f32_16x16x32_bf16(al, bh, acc[nt][mt], 0, 0, 0);
        }
      }
    } else {
#pragma unroll
      for (int mt = 0; mt < 4; mt++) {
        const int ar = (mt * 16 + ml) * AP + ko;
        bf16x8 ah = *(const bf16x8*)&Ah_s[ar];
#pragma unroll
        for (int nt = 0; nt < 2; nt++) {
          const int br = (wave * 32 + nt * 16 + ml) * AP + ko;
          bf16x8 bh = *(const bf16x8*)&Bh_s[br];
          bf16x8 bl = *(const bf16x8*)&Bl_s[br];
          acc[nt][mt] = __builtin_amdgcn_mfma_f32_16x16x32_bf16(ah, bh, acc[nt][mt], 0, 0, 0);
          acc[nt][mt] = __builtin_amdgcn_mfma_f32_16x16x32_bf16(ah, bl, acc[nt][mt], 0, 0, 0);
        }
      }
    }
  }
  __syncthreads();   // phase-B LDS reads complete before hnT overwrites ms

  // ---- epilogue: hn + h write + hnT + fused group-sum
#pragma unroll
  for (int nt = 0; nt < 2; nt++) {
    const int ch = wave * 32 + nt * 16 + ml;
#pragma unroll
    for (int mt = 0; mt < 4; mt++) {
      int lrb = mt * 16 + quad * 4;
      int rbase = nBase + lrb;
      float runv = 0.f;
      int curb = -1;
#pragma unroll
      for (int q = 0; q < 4; q++) {
        int nd = rbase + q;
        short hv = 0;
        if (nd < Nn) {
          int bi = batch[nd];
          float u = fmaxf(acc[nt][mt][q] + gbs[bi * 128 + ch], 0.f);
          float hn = h[(size_t)nd * 128 + ch] + u;
          h[(size_t)nd * 128 + ch] = hn;
          hv = f2bf(hn);
          if (bi != curb) {
            if (curb >= 0) atomicAdd(&ls[curb * 128 + ch], runv);
            curb = bi;
            runv = 0.f;
          }
          runv += hn;
        }
        hnT[(lrb + q) * HTT + ch] = hv;
      }
      if (curb >= 0) atomicAdd(&ls[curb * 128 + ch], runv);
    }
  }
  __syncthreads();   // hnT + ls complete
#pragma unroll
  for (int q = 0; q < 4; q++) {
    int idx = t + q * 256;
    float v = ls[idx];
    if (v != 0.f) atomicAdd(&gsum_out[idx], v);
  }

  // ---- phase C: proj of the NEW h (skipped on last round)
  if (doproj) {
#pragma unroll 1
    for (int y = 0; y < 2; y++) {
      f32x4 pacc[2][4];
#pragma unroll
      for (int nt = 0; nt < 2; nt++)
#pragma unroll
        for (int mt = 0; mt < 4; mt++)
#pragma unroll
          for (int q = 0; q < 4; q++) pacc[nt][mt][q] = 0.f;
#pragma unroll
      for (int c = 0; c < 4; c++) {
        const bf16x8 b0 = *(const bf16x8*)&Wmth[(size_t)(y * 128 + wave * 32 + ml) * 128 + c * 32 + ko];
        const bf16x8 b1 = *(const bf16x8*)&Wmth[(size_t)(y * 128 + wave * 32 + 16 + ml) * 128 + c * 32 + ko];
#pragma unroll
        for (int mt = 0; mt < 4; mt++) {
          bf16x8 ah = *(const bf16x8*)&hnT[(mt * 16 + ml) * HTT + c * 32 + ko];
          pacc[0][mt] = __builtin_amdgcn_mfma_f32_16x16x32_bf16(ah, b0, pacc[0][mt], 0, 0, 0);
          pacc[1][mt] = __builtin_amdgcn_mfma_f32_16x16x32_bf16(ah, b1, pacc[1][mt], 0, 0, 0);
        }
      }
      if (y == 0) {
#pragma unroll
        for (int nt = 0; nt < 2; nt++) {
          const int ch = wave * 32 + nt * 16 + ml;
#pragma unroll
          for (int mt = 0; mt < 4; mt++) {
#pragma unroll
            for (int q = 0; q < 4; q++) {
              int nd = nBase + mt * 16 + quad * 4 + q;
              if (nd < Nn) {
                int pk = __builtin_amdgcn_cvt_pk_fp8_f32(pacc[nt][mt][q], pacc[nt][mt][q], 0, false);
                hs8[(size_t)nd * 128 + ch] = (unsigned char)(pk & 0xff);
              }
            }
          }
        }
      } else {
#pragma unroll
        for (int nt = 0; nt < 2; nt++) {
          const int ch = wave * 32 + nt * 16 + ml;
#pragma unroll
          for (int mt = 0; mt < 4; mt++) {
#pragma unroll
            for (int q = 0; q < 4; q++) {
              int nd = nBase + mt * 16 + quad * 4 + q;
              if (nd < Nn) hdbf[(size_t)nd * 128 + ch] = (unsigned short)f2bf(pacc[nt][mt][q]);
            }
          }
        }
      }
    }
  }
}

// ---------------------------------------------------------------- kwv (MFMA bf16) + fused decode
__global__ __launch_bounds__(256) void kwv_kernel(
    const float* __restrict__ h, const float* __restrict__ pos,
    const float* __restrict__ Fm, const float* __restrict__ Wd,
    const float* __restrict__ bd, float* __restrict__ partial,
    float* __restrict__ ksum, float* __restrict__ out) {
  __shared__ float h_s[32 * HP];     // fp32 tile for decode
  __shared__ short nkT[128 * KS];    // A: nkT[m][k]
  __shared__ short hT[128 * KS];     // B: hT[n][k]
  __shared__ float wd[512];
  __shared__ float ksum_s[128];
  __shared__ float dsum[256];
  const int t = threadIdx.x;
  const int hr = t >> 3;
  const int hc = (t & 7) * 16;
  const int fg = (t & 7) * 8;
  const int wave = t >> 6, lane = t & 63;
  const int ml = lane & 15, quad = lane >> 4;
  const int ko = quad * 8;
  if (t < 128) { *(float4*)&wd[t * 4] = *(const float4*)&Wd[t * 4]; ksum_s[t] = 0.f; }
  const float bdv = bd[t & 3];
  const int dn = (t & 127) >> 2, dno = t & 3;     // decode output (node-in-tile, out)
  const int dk0 = (t >> 7) * 64;                  // decode k half
  f32x4 acc[2][8];
#pragma unroll
  for (int nt = 0; nt < 2; nt++)
#pragma unroll
    for (int mt = 0; mt < 8; mt++)
#pragma unroll
      for (int q = 0; q < 4; q++) acc[nt][mt][q] = 0.f;
  float klc[8], kls[8];
#pragma unroll
  for (int f = 0; f < 8; f++) { klc[f] = 0.f; kls[f] = 0.f; }

  int ptile = -1;
  const int nTiles = (Nn + 31) / 32;  // 1563
  for (int tile = blockIdx.x; tile < nTiles; tile += gridDim.x) {
    const int gh = tile * 32 + hr;
    float4 hv0 = {0.f, 0.f, 0.f, 0.f}, hv1 = hv0, hv2 = hv0, hv3 = hv0;
    float cbuf[8], sbuf[8];
    if (gh < Nn) {
      const float* hp = &h[(size_t)gh * 128 + hc];
      hv0 = *(const float4*)(hp + 0);
      hv1 = *(const float4*)(hp + 4);
      hv2 = *(const float4*)(hp + 8);
      hv3 = *(const float4*)(hp + 12);
      const float px = pos[gh * 2 + 0], py = pos[gh * 2 + 1];
#pragma unroll
      for (int f = 0; f < 8; f++) {
        float p = px * Fm[fg + f] + py * Fm[64 + fg + f];
        cbuf[f] = cosf(p) * 0.125f;
        sbuf[f] = sinf(p) * 0.125f;
      }
    } else {
#pragma unroll
      for (int f = 0; f < 8; f++) { cbuf[f] = 0.f; sbuf[f] = 0.f; }
    }
    float xs[16] = {hv0.x,hv0.y,hv0.z,hv0.w, hv1.x,hv1.y,hv1.z,hv1.w,
                    hv2.x,hv2.y,hv2.z,hv2.w, hv3.x,hv3.y,hv3.z,hv3.w};
    __syncthreads();  // prev tile's LDS reads & dsum writes done
    if (ptile >= 0 && t < 128) {
      int gn = ptile * 32 + dn;
      if (gn < Nn) out[4 + (size_t)gn * 4 + dno] = dsum[t] + dsum[t + 128] + bdv;
    }
    *(float4*)&h_s[hr * HP + hc + 0]  = hv0;
    *(float4*)&h_s[hr * HP + hc + 4]  = hv1;
    *(float4*)&h_s[hr * HP + hc + 8]  = hv2;
    *(float4*)&h_s[hr * HP + hc + 12] = hv3;
#pragma unroll
    for (int i = 0; i < 16; i++) hT[(hc + i) * KS + hr] = f2bf(xs[i]);
#pragma unroll
    for (int f = 0; f < 8; f++) {
      nkT[(fg + f) * KS + hr] = f2bf(cbuf[f]);
      nkT[(64 + fg + f) * KS + hr] = f2bf(sbuf[f]);
      klc[f] += cbuf[f];
      kls[f] += sbuf[f];
    }
    __syncthreads();
#pragma unroll
    for (int mt = 0; mt < 8; mt++) {
      bf16x8 ah = *(const bf16x8*)&nkT[(mt * 16 + ml) * KS + ko];
#pragma unroll
      for (int nt = 0; nt < 2; nt++) {
        bf16x8 bh = *(const bf16x8*)&hT[(wave * 32 + nt * 16 + ml) * KS + ko];
        acc[nt][mt] = __builtin_amdgcn_mfma_f32_16x16x32_bf16(ah, bh, acc[nt][mt], 0, 0, 0);
      }
    }
    {  // decode partial: 64-deep half-loop on all 256 threads
      float s = 0.f;
#pragma unroll 4
      for (int kk = dk0; kk < dk0 + 64; kk++) {
        int k = (kk + dn) & 127;
        s = fmaf(h_s[dn * HP + k], wd[k * 4 + dno], s);
      }
      dsum[t] = s;
    }
    ptile = tile;
  }
  __syncthreads();
  if (ptile >= 0 && t < 128) {  // drain last tile
    int gn = ptile * 32 + dn;
    if (gn < Nn) out[4 + (size_t)gn * 4 + dno] = dsum[t] + dsum[t + 128] + bdv;
  }
  float* pb = &partial[(size_t)blockIdx.x * 16384];
#pragma unroll
  for (int nt = 0; nt < 2; nt++) {
    const int col = wave * 32 + nt * 16 + ml;
#pragma unroll
    for (int mt = 0; mt < 8; mt++) {
#pragma unroll
      for (int q = 0; q < 4; q++) {
        int row = mt * 16 + quad * 4 + q;
        pb[row * 128 + col] = acc[nt][mt][q];
      }
    }
  }
#pragma unroll
  for (int f = 0; f < 8; f++) {
    atomicAdd(&ksum_s[fg + f], klc[f]);
    atomicAdd(&ksum_s[64 + fg + f], kls[f]);
  }
  __syncthreads();
  if (t < 128) atomicAdd(&ksum[t], ksum_s[t]);
}

__global__ __launch_bounds__(256) void kwv_reduce(const float* __restrict__ partial,
                                                  float* __restrict__ kwv) {
  int idx = blockIdx.x * 256 + threadIdx.x;
  float s = 0.f;
  for (int b = 0; b < KWVB; b++) s += partial[(size_t)b * 16384 + idx];
  kwv[idx] = s;
}

// ---------------------------------------------------------------- final sampling head
__global__ __launch_bounds__(128) void final_kernel(
    const float* __restrict__ sp, const float* __restrict__ Fm,
    const float* __restrict__ kwv, const float* __restrict__ vs,
    const float* __restrict__ ksum, const float* __restrict__ Wd,
    const float* __restrict__ bd, float* __restrict__ out) {
  __shared__ float nq_s[128];
  __shared__ float red[2];
  __shared__ float redU[8];
  int t = threadIdx.x;
  int jj = t & 63;
  float p = sp[0] * Fm[jj] + sp[1] * Fm[64 + jj];
  nq_s[t] = ((t < 64) ? cosf(p) : sinf(p)) * 0.125f;  // ||q||=sqrt(0.5) exact
  __syncthreads();
  float num = 0.f;
#pragma unroll
  for (int g = 0; g < Bb; g++) num += vs[g * 128 + t];
  for (int k = 0; k < 128; k++) num = fmaf(nq_s[k], kwv[k * 128 + t], num);
  float dp = nq_s[t] * ksum[t];
#pragma unroll
  for (int off = 32; off > 0; off >>= 1) dp += __shfl_down(dp, off);
  if ((t & 63) == 0) red[t >> 6] = dp;
  __syncthreads();
  float den = (float)Nn + red[0] + red[1];
  float e = num / den;
  float u[4];
#pragma unroll
  for (int o = 0; o < 4; o++) u[o] = e * Wd[t * 4 + o];
#pragma unroll
  for (int off = 32; off > 0; off >>= 1) {
#pragma unroll
    for (int o = 0; o < 4; o++) u[o] += __shfl_down(u[o], off);
  }
  if ((t & 63) == 0) {
#pragma unroll
    for (int o = 0; o < 4; o++) redU[(t >> 6) * 4 + o] = u[o];
  }
  __syncthreads();
  if (t < 4) out[t] = redU[t] + redU[4 + t] + bd[t];
}

// ---------------------------------------------------------------- launcher
extern "C" void kernel_launch(void* const* d_in, const int* in_sizes, int n_in,
                              void* d_out, int out_size, void* d_ws, size_t ws_size,
                              hipStream_t stream) {
  const float* x    = (const float*)d_in[0];
  const float* xm   = (const float*)d_in[1];
  const int*   ei   = (const int*)d_in[2];
  const float* ea   = (const float*)d_in[3];
  const float* pos  = (const float*)d_in[4];
  const int*   batch= (const int*)d_in[5];
  const float* sp   = (const float*)d_in[6];
  const float* Fm   = (const float*)d_in[7];
  const float* Wenc = (const float*)d_in[8];
  const float* benc = (const float*)d_in[9];
  const float* Wmsg = (const float*)d_in[10];
  const float* bmsg = (const float*)d_in[11];
  const float* Wupd = (const float*)d_in[12];
  const float* bupd = (const float*)d_in[13];
  const float* Wdec = (const float*)d_in[14];
  const float* bdec = (const float*)d_in[15];
  float* out = (float*)d_out;

  float* ws     = (float*)d_ws;
  float* h      = ws;                              // N*128
  float* agg    = h + (size_t)Nn * 128;            // region: aggbf (12.8MB); kwv partials span
  float* aux    = agg + (size_t)Nn * 128;          // region: hs8 (6.4MB) + hdbf (12.8MB)
  float* invdeg = aux + (size_t)Nn * 128;          // N
  // ---- zeroed region (6808 x 4B, one memset) ----
  float* gsum   = invdeg + Nn;                     // 1024
  float* gcnt   = gsum + 1024;                     // 8
  float* bcsum  = gcnt + 8;                        // 1024
  float* bccnt  = bcsum + 1024;                    // 8
  float* gsumR  = bccnt + 8;                       // 4*1024
  float* vsum   = gsumR + 4096;                    // 128 (unused)
  float* ksum   = vsum + 128;                      // 128
  int*   bktcnt = (int*)(ksum + 128);              // 196
  int*   bktcur = bktcnt + 196;                    // 196 (offset cursors, start 0)
  // ---- end zeroed region ----
  float* gbst   = (float*)(bktcur + 196);          // 1024
  float* gbuf   = gbst + 1024;                     // 4*1024
  float* kwv    = gbuf + 4096;                     // 16384
  int2*  rec    = (int2*)(kwv + 16384);            // E (packed 8B, CSR order)
  int*   cnt    = (int*)(rec + Ee);                // N
  int*   rowptr = cnt + Nn;                        // N+1
  int*   bsum   = rowptr + Nn + 1;                 // 256
  short* wmt_h  = (short*)(bsum + 256);            // 2*128*128
  short* wmt_l  = wmt_h + 32768;
  short* wut_h  = wmt_l + 32768;                   // 128*256
  short* wut_l  = wut_h + 32768;
  int2*  recA   = (int2*)(wut_l + 32768);          // E (bucket-partitioned staging)
  unsigned char* dlo = (unsigned char*)(recA + Ee);// E

  unsigned short* aggbf = (unsigned short*)agg;                     // 12.8 MB
  unsigned char*  hs8   = (unsigned char*)aux;                      // 6.4 MB
  unsigned short* hdbf  = (unsigned short*)(hs8 + (size_t)Nn * 128);// 12.8 MB

  hipMemsetAsync(gsum, 0, 6808 * 4, stream);

  const int nb128 = (Nn + 127) / 128;  // 391
  const int nb64  = (Nn + 63) / 64;    // 782

  // D1: CSR bucket-count + weight split  ||  encode + segmean
  csr_enc<<<P1B + nb128, 256, 0, stream>>>(
      ei, bktcnt, Wmsg, Wupd, wmt_h, wmt_l, wut_h, wut_l,
      x, xm, batch, Wenc, benc, h, gsum, gcnt, bcsum, bccnt);

  // D2: bkt_part (local scan)  ||  round-0 proj (+gbst/gb0)
  part_proj<<<P1B + nb64, 256, 0, stream>>>(
      ei, ea, bktcnt, bktcur, recA, dlo,
      h, wmt_h, hs8, hdbf,
      bcsum, bccnt, bupd, Wupd, gbst, gsum, gcnt, gbuf);

  // D3/D4: per-dst counts + rowptr/scatter (scans computed locally)
  dst_cnt_bsum<<<NBK, 256, 0, stream>>>(bktcnt, dlo, cnt, bsum);
  apply_fin<<<NBK, 256, 0, stream>>>(cnt, bsum, bktcnt, recA, dlo,
                                     rowptr, invdeg, rec);

  for (int r = 0; r < ROUNDS; r++) {
    // agg blocks 0..7 compute gb_r for r>=1 (updg_{r-1} completed -> gsumR ready)
    agg_kernel<<<(Nn + 7) / 8, 256, 0, stream>>>(
        hs8, hdbf, aggbf, rec, rowptr, invdeg, Wmsg, bmsg,
        Wupd, gbst,
        (r == 0) ? gsum : (gsumR + (size_t)(r - 1) * 1024), gcnt,
        gbuf + (size_t)r * 1024, (r >= 1) ? 1 : 0);
    updg_proj<<<nb64, 256, 0, stream>>>(
        h, aggbf, batch, wut_h, wut_l,
        gbuf + (size_t)r * 1024, gsumR + (size_t)r * 1024,
        wmt_h, hs8, hdbf, (r < ROUNDS - 1) ? 1 : 0);
  }

  // kwv partials alias the (now free) agg+aux regions: 512*64KB = 33.5 MB < 51.2 MB
  kwv_kernel<<<KWVB, 256, 0, stream>>>(h, pos, Fm, Wdec, bdec, agg, ksum, out);
  kwv_reduce<<<64, 256, 0, stream>>>(agg, kwv);
  final_kernel<<<1, 128, 0, stream>>>(sp, Fm, kwv, gsumR + 3 * 1024, ksum,
                                      Wdec, bdec, out);
}